// Round 2
// baseline (13789.574 us; speedup 1.0000x reference)
//
#include <hip/hip_runtime.h>

typedef float f32x4 __attribute__((ext_vector_type(4)));

namespace {
constexpr int Bn = 64, Sn = 512, Fn = 128, Hn = 512;
constexpr int NWG = 256, NTHR = 1024;
constexpr int HXS = 644;     // hx row stride (dwords), 16B-aligned
constexpr int PQS = 581;     // part q-plane stride (dwords): 581%32=5 -> spread banks
constexpr int RING0 = 1024;  // ring base offset in dwords (first 4 KB = counters)
constexpr int GRP_RING = 8192;  // dwords per group: 2 slots x 8 batches x 512
}

__device__ __forceinline__ float sigmoid_f(float v) {
    return 1.0f / (1.0f + __expf(-v));
}
__device__ __forceinline__ float tanh_f(float v) {
    v = fminf(fmaxf(v, -15.0f), 15.0f);
    const float e = __expf(-2.0f * v);
    return (1.0f - e) / (1.0f + e);
}

// Persistent LSTM, 1 WG/CU (LDS 98KB forces it), 256 WGs = 256 CUs.
//  - 1024 threads (16 waves/CU, 4/SIMD) to cover LDS/VMEM latency: GEMM batch
//    dim split in half per thread (acc[4][4]).
//  - __launch_bounds__(1024, 4): 4 waves/SIMD == our actual residency (LDS
//    forces 1 WG/CU) -> VGPR cap 128. Round-1 bug: omitting the 2nd arg let
//    the compiler cap at 64 VGPRs, evicting wreg[4][5] (80 VGPRs) and
//    re-reading weights from memory every step (FETCH_SIZE 2x, dur +50%).
//  - Batch groups formed by PHYSICAL XCD (HW_REG_XCC_ID + atomic ticket):
//    group g owns batches 8g..8g+7; its 32 WGs share one L2, so the h ring
//    uses sc0-only ops (XCD-local L2) instead of sc1/L3. Ring is fully
//    written in-kernel before being read -> no pre-launch cache-state
//    dependence. 32 WGs/XCD guaranteed by capacity (1 WG/CU, 32 CUs/XCD).
//  - Grid barrier: single-level, 32 same-XCD WGs, counters in L3 (agent
//    scope, memset-coherent). Bounded spin -> fail loud, never hang.
//  - Cell update on 256 threads (gate-pair split + shfl_xor), out-projection
//    on 512 threads (16 K-slices of 32).
__global__ __launch_bounds__(NTHR, 4)
void lstm_persist(const float* __restrict__ x,     // [B,S,F]
                  const float* __restrict__ Wih,   // [4H,F]
                  const float* __restrict__ Whh,   // [4H,H]
                  const float* __restrict__ bih,   // [4H]
                  const float* __restrict__ bhh,   // [4H]
                  const float* __restrict__ Wout,  // [F,H]
                  const float* __restrict__ bout,  // [F]
                  float* __restrict__ out,         // [B,S,F]
                  float* __restrict__ ws)          // [counters 4KB][per-group h rings]
{
    const int t = threadIdx.x;

    // ---- dynamic group assignment: group = physical XCD, slot = ticket ----
    __shared__ int s_grp[2];
    if (t == 0) {
        // hwreg(HW_REG_XCC_ID=20, offset 0, size 4)
        const unsigned xcc =
            (unsigned)__builtin_amdgcn_s_getreg(20 | (0 << 6) | (3 << 11)) & 7u;
        unsigned* slotp = (unsigned*)ws + 256 + 32 * xcc;  // memset-covered
        s_grp[0] = (int)xcc;
        s_grp[1] = (int)(atomicAdd(slotp, 1u) & 31u);      // agent scope (L3)
    }
    __syncthreads();
    const int bw = s_grp[0];  // batch group == XCD, [0,8)
    const int rw = s_grp[1];  // row slot within XCD, [0,32)

    unsigned* const gcnt = (unsigned*)ws + 32 * bw;        // own 128B line
    float* const ring = ws + RING0 + (size_t)bw * GRP_RING;

    // GEMM decomposition: q = K-slice [20q,20q+20), r4 = row-quad, bh = batch half
    const int q  = t & 31;
    const int r4 = (t >> 5) & 15;
    const int bh = t >> 9;
    const int k0 = 20 * q;

    // out-projection decomposition (threads 0..511: 4 feats x 8 batches x 16 K-slices)
    const int out_fi  = (t >> 1) & 3;
    const int out_bb  = (t >> 3) & 7;
    const int out_ksl = ((t >> 6) << 1) | (t & 1);

    __shared__ float hx[8][HXS];       // staged [h(512) | x(128)] per local batch
    __shared__ float part[32 * PQS];   // gate partials: part[q*PQS + row*9 + batch]
    __shared__ float opart[4][8][17];  // out partials [fi][batch][ksl(+pad)]
    __shared__ float gb[64];           // gate biases
    __shared__ float cst[16][9];       // c state [unit][batch(+pad)]
    __shared__ float bo[4];            // out biases

    // ---- one-time weight preload into registers: 4 rows x 5 quads (K=20) ----
    // (bh=0/1 threads with same (q,r4) intentionally hold identical weights)
    f32x4 wreg[4][5];
#pragma unroll
    for (int i = 0; i < 4; ++i) {
        const int r = 4 * r4 + i;                          // row in WG [0,64)
        const int G = (r >> 4) * Hn + rw * 16 + (r & 15);  // global gate row
#pragma unroll
        for (int j = 0; j < 5; ++j) {
            const int kk = k0 + 4 * j;
            if (kk < Hn) wreg[i][j] = *(const f32x4*)(Whh + (size_t)G * Hn + kk);
            else         wreg[i][j] = *(const f32x4*)(Wih + (size_t)G * Fn + (kk - Hn));
        }
    }

    if (t < 64) {
        const int G = (t >> 4) * Hn + rw * 16 + (t & 15);
        gb[t] = bih[G] + bhh[G];
    }
    if (t < 4) bo[t] = bout[rw * 4 + t];
    if (t < 128) cst[t >> 3][t & 7] = 0.0f;

    // ---- zero h_{-1} (ring slot 1) via XCD-local L2 ----
    if (t < 128) {
        const int ul = t & 15, bbc = (t >> 4) & 7;
        float* hdst = ring + 4096 + (size_t)bbc * 512 + (16 * rw + ul);
        const float z = 0.0f;
        asm volatile("global_store_dword %0, %1, off sc0"
                     :: "v"(hdst), "v"(z) : "memory");
    }
    asm volatile("s_waitcnt vmcnt(0)" ::: "memory");
    __syncthreads();
    // ---- init barrier: 32 same-XCD WGs, generation 1 ----
    if (t == 0) atomicAdd(gcnt, 1u);  // agent scope -> L3, memset-coherent
    {
        int guard = 0;
        while (__hip_atomic_load(gcnt, __ATOMIC_RELAXED,
                                 __HIP_MEMORY_SCOPE_AGENT) < 32u) {
            __builtin_amdgcn_s_sleep(1);
            if (++guard > 1000000) break;
        }
    }

    for (int k = 0; k <= Sn; ++k) {
        // ---- stage h_{k-1} (ring slot (k&1)^1): one f32x4/thread, L2-local ----
        const int slot = (k & 1) ^ 1;
        {
            const float* p0 = ring + (size_t)slot * 4096 + 4 * t;
            f32x4 v0;
            asm volatile("global_load_dwordx4 %0, %1, off sc0\n\t"
                         "s_waitcnt vmcnt(0)"
                         : "=&v"(v0) : "v"(p0) : "memory");
            *(f32x4*)&hx[t >> 7][(t & 127) * 4] = v0;
        }
        if (k < Sn && t < 256) {  // stage x[:,k,:] for our 8 batches (cached loads)
            const int bbs = t >> 5, f4 = (t & 31) * 4;
            const f32x4 v = *(const f32x4*)(x + (size_t)(8 * bw + bbs) * Sn * Fn +
                                            (size_t)k * Fn + f4);
            *(f32x4*)&hx[bbs][Hn + f4] = v;
        }
        __syncthreads();

        // ---- gate GEMM: acc[4 rows][4 batches] over K-slice [k0,k0+20) ----
        if (k < Sn) {
            float acc[4][4];
#pragma unroll
            for (int i = 0; i < 4; ++i)
#pragma unroll
                for (int ib = 0; ib < 4; ++ib) acc[i][ib] = 0.0f;
#pragma unroll
            for (int j = 0; j < 5; ++j) {
                f32x4 hv[4];
#pragma unroll
                for (int ib = 0; ib < 4; ++ib)
                    hv[ib] = *(const f32x4*)&hx[4 * bh + ib][k0 + 4 * j];
#pragma unroll
                for (int i = 0; i < 4; ++i)
#pragma unroll
                    for (int ib = 0; ib < 4; ++ib)
                        acc[i][ib] += wreg[i][j].x * hv[ib].x + wreg[i][j].y * hv[ib].y +
                                      wreg[i][j].z * hv[ib].z + wreg[i][j].w * hv[ib].w;
            }
#pragma unroll
            for (int i = 0; i < 4; ++i)
#pragma unroll
                for (int ib = 0; ib < 4; ++ib)
                    part[q * PQS + (4 * r4 + i) * 9 + (4 * bh + ib)] = acc[i][ib];
        }

        // ---- pipelined out-projection for step k-1 (uses staged h_{k-1}) ----
        if (k >= 1 && t < 512) {
            const float* wo = Wout + (size_t)(rw * 4 + out_fi) * Hn + out_ksl * 32;
            const float* hrow = &hx[out_bb][out_ksl * 32];
            float oa = 0.0f;
#pragma unroll
            for (int jj = 0; jj < 8; ++jj) {
                const f32x4 wv = *(const f32x4*)(wo + 4 * jj);
                const f32x4 hv = *(const f32x4*)(hrow + 4 * jj);
                oa += wv.x * hv.x + wv.y * hv.y + wv.z * hv.z + wv.w * hv.w;
            }
            opart[out_fi][out_bb][out_ksl] = oa;
        }
        __syncthreads();

        // ---- cell update (t<256, gate-pair split + shfl) ----
        if (k < Sn && t < 256) {
            const int gh = t & 1, ul = (t >> 1) & 15, bbc = (t >> 5) & 7;
            const int r0 = (2 * gh) * 16 + ul, r1 = (2 * gh + 1) * 16 + ul;
            float s0 = gb[r0], s1 = gb[r1];
#pragma unroll
            for (int qq = 0; qq < 32; ++qq) {
                s0 += part[qq * PQS + r0 * 9 + bbc];
                s1 += part[qq * PQS + r1 * 9 + bbc];
            }
            const float o0 = __shfl_xor(s0, 1, 64);
            const float o1 = __shfl_xor(s1, 1, 64);
            if (gh == 0) {
                const float ig = sigmoid_f(s0);
                const float fg = sigmoid_f(s1);
                const float gg = tanh_f(o0);
                const float og = sigmoid_f(o1);
                const float cn = fg * cst[ul][bbc] + ig * gg;
                cst[ul][bbc] = cn;
                const float hn = og * tanh_f(cn);
                float* hdst = ring + (size_t)(k & 1) * 4096 +
                              (size_t)bbc * 512 + (16 * rw + ul);
                asm volatile("global_store_dword %0, %1, off sc0"
                             :: "v"(hdst), "v"(hn) : "memory");
            }
        } else if (k >= 1 && t >= 256 && t < 288) {
            // ---- out finalize for step k-1 ----
            const int fi = (t - 256) >> 3, bbo = (t - 256) & 7;
            float s = bo[fi];
#pragma unroll
            for (int qq = 0; qq < 16; ++qq) s += opart[fi][bbo][qq];
            out[(size_t)(8 * bw + bbo) * Sn * Fn + (size_t)(k - 1) * Fn +
                rw * 4 + fi] = s;
        }

        // ---- single-level 32-WG (same-XCD) barrier, all waves poll ----
        if (k < Sn) {
            asm volatile("s_waitcnt vmcnt(0)" ::: "memory");  // h stores are in L2
            __syncthreads();
            if (t == 0) atomicAdd(gcnt, 1u);
            const unsigned target = 32u * (unsigned)(k + 2);
            int guard = 0;
            while (__hip_atomic_load(gcnt, __ATOMIC_RELAXED,
                                     __HIP_MEMORY_SCOPE_AGENT) < target) {
                __builtin_amdgcn_s_sleep(1);
                if (++guard > 100000) break;  // fail loud (wrong data), never hang
            }
        }
    }
}

extern "C" void kernel_launch(void* const* d_in, const int* in_sizes, int n_in,
                              void* d_out, int out_size, void* d_ws, size_t ws_size,
                              hipStream_t stream) {
    (void)in_sizes; (void)n_in; (void)out_size; (void)ws_size;
    const float* x    = (const float*)d_in[0];
    const float* Wih  = (const float*)d_in[1];
    const float* Whh  = (const float*)d_in[2];
    const float* bih  = (const float*)d_in[3];
    const float* bhh  = (const float*)d_in[4];
    const float* Wout = (const float*)d_in[5];
    const float* bout = (const float*)d_in[6];
    float* outp = (float*)d_out;
    float* wsp  = (float*)d_ws;  // [4 KB counters+tickets][8 x 32 KB group h rings]

    hipMemsetAsync(d_ws, 0, 4096, stream);  // barrier counters + slot tickets

    lstm_persist<<<dim3(NWG), dim3(NTHR), 0, stream>>>(
        x, Wih, Whh, bih, bhh, Wout, bout, outp, wsp);
}

// Round 3
// 8217.256 us; speedup vs baseline: 1.6781x; 1.6781x over previous
//
#include <hip/hip_runtime.h>

typedef float f32x4 __attribute__((ext_vector_type(4)));

namespace {
constexpr int Bn = 64, Sn = 512, Fn = 128, Hn = 512;
constexpr int NWG = 512, NTHR = 512;
constexpr int HXS = 644;     // hx row stride (dwords): %32==4 -> batch rows tile banks
constexpr int PQS = 293;     // part q-plane stride (dwords): 32 rows*9 + 5, odd mod 32
constexpr int RING0 = 1024;  // ring base offset in dwords (first 4 KB = counters)
constexpr int GRP_RING = 8192;  // dwords per group: 2 slots x 8 batches x 512
}

__device__ __forceinline__ float sigmoid_f(float v) {
    return 1.0f / (1.0f + __expf(-v));
}
__device__ __forceinline__ float tanh_f(float v) {
    v = fminf(fmaxf(v, -15.0f), 15.0f);
    const float e = __expf(-2.0f * v);
    return (1.0f - e) / (1.0f + e);
}

// Persistent LSTM, 512 WGs x 512 thr = 2 WGs/CU (16 waves/CU, 4/SIMD).
// Round-1/2 lesson: at 1024 thr the allocator pins VGPR=64 regardless of
// __launch_bounds__ min-waves (wreg evicted -> weights re-read every step,
// FETCH 2x, dur +50%). At 512 thr + bounds(512,*) it reliably gave 128
// (round 0). So occupancy comes from 2 co-resident 512-thr WGs instead:
//  - per-WG work halved in the row dim: 8 hidden units (32 gate rows) +
//    2 out-features per WG; wreg[2][5]=40 VGPRs -> total ~95 regs. Even a
//    64-reg cap only causes mild spill; >128 never needed -> 2 WGs/CU always
//    fit (LDS 60KB/WG <= 80KB) -> no capacity deadlock.
//  - the 2 WGs/CU are NOT barrier-synced with each other: while one waits in
//    the grid barrier the other's waves use the SIMDs (latency overlap).
//  - batch group = physical XCD (XCC_ID + ticket): 64 WGs/XCD share one L2;
//    h ring uses sc0-only ops (XCD-local L2). Ring fully written in-kernel
//    before read -> no pre-launch cache-state dependence. Capacity: 2 WG/CU
//    x 32 CU = 64 WGs/XCD exactly.
//  - single-level 64-WG barrier; counters agent-scope in L3 (memset-coherent);
//    only t==0 polls (all-thread polling hammered L3); bounded spin-> fail loud.
__global__ __launch_bounds__(NTHR, 4)
void lstm_persist(const float* __restrict__ x,     // [B,S,F]
                  const float* __restrict__ Wih,   // [4H,F]
                  const float* __restrict__ Whh,   // [4H,H]
                  const float* __restrict__ bih,   // [4H]
                  const float* __restrict__ bhh,   // [4H]
                  const float* __restrict__ Wout,  // [F,H]
                  const float* __restrict__ bout,  // [F]
                  float* __restrict__ out,         // [B,S,F]
                  float* __restrict__ ws)          // [counters 4KB][per-group h rings]
{
    const int t = threadIdx.x;

    // ---- dynamic group assignment: group = physical XCD, slot = ticket ----
    __shared__ int s_grp[2];
    if (t == 0) {
        // hwreg(HW_REG_XCC_ID=20, offset 0, size 4)
        const unsigned xcc =
            (unsigned)__builtin_amdgcn_s_getreg(20 | (0 << 6) | (3 << 11)) & 7u;
        unsigned* slotp = (unsigned*)ws + 256 + 32 * xcc;  // memset-covered
        s_grp[0] = (int)xcc;
        s_grp[1] = (int)(atomicAdd(slotp, 1u) & 63u);      // agent scope (L3)
    }
    __syncthreads();
    const int bw = s_grp[0];  // batch group == XCD, [0,8)
    const int rw = s_grp[1];  // row slot within XCD, [0,64)

    unsigned* const gcnt = (unsigned*)ws + 32 * bw;        // own 128B line
    float* const ring = ws + RING0 + (size_t)bw * GRP_RING;

    // GEMM decomposition: q = K-slice [20q,20q+20), r2 = row-pair index
    const int q  = t & 31;
    const int r2 = t >> 5;    // [0,16): owns rows 2r2, 2r2+1 of the WG's 32
    const int k0 = 20 * q;

    // out-projection decomposition (threads 0..255: 2 feats x 8 batches x 16 K-slices)
    const int out_fi  = t & 1;
    const int out_bb  = (t >> 1) & 7;
    const int out_ksl = t >> 4;          // [0,16) for t<256, K=32 each

    __shared__ float hx[8][HXS];       // staged [h(512) | x(128)] per local batch
    __shared__ float part[32 * PQS];   // gate partials: part[q*PQS + row*9 + batch]
    __shared__ float opart[2][8][17];  // out partials [fi][batch][ksl(+pad)]
    __shared__ float gb[32];           // gate biases (32 rows)
    __shared__ float cst[8][9];        // c state [unit][batch(+pad)]
    __shared__ float bo[2];            // out biases

    // ---- one-time weight preload into registers: 2 rows x 5 quads (K=20) ----
    f32x4 wreg[2][5];
#pragma unroll
    for (int i = 0; i < 2; ++i) {
        const int r = 2 * r2 + i;                         // row in WG [0,32)
        const int G = (r >> 3) * Hn + rw * 8 + (r & 7);   // global gate row
#pragma unroll
        for (int j = 0; j < 5; ++j) {
            const int kk = k0 + 4 * j;
            if (kk < Hn) wreg[i][j] = *(const f32x4*)(Whh + (size_t)G * Hn + kk);
            else         wreg[i][j] = *(const f32x4*)(Wih + (size_t)G * Fn + (kk - Hn));
        }
    }

    if (t < 32) {
        const int G = (t >> 3) * Hn + rw * 8 + (t & 7);
        gb[t] = bih[G] + bhh[G];
    }
    if (t < 2) bo[t] = bout[rw * 2 + t];
    if (t < 64) cst[t >> 3][t & 7] = 0.0f;

    // ---- zero h_{-1} (ring slot 1) via XCD-local L2: our 8 units x 8 batches ----
    if (t < 64) {
        const int ul = t & 7, bbc = t >> 3;
        float* hdst = ring + 4096 + (size_t)bbc * 512 + (8 * rw + ul);
        const float z = 0.0f;
        asm volatile("global_store_dword %0, %1, off sc0"
                     :: "v"(hdst), "v"(z) : "memory");
    }
    asm volatile("s_waitcnt vmcnt(0)" ::: "memory");
    __syncthreads();
    // ---- init barrier: 64 same-XCD WGs, generation 1 ----
    if (t == 0) {
        atomicAdd(gcnt, 1u);  // agent scope -> L3, memset-coherent
        int guard = 0;
        while (__hip_atomic_load(gcnt, __ATOMIC_RELAXED,
                                 __HIP_MEMORY_SCOPE_AGENT) < 64u) {
            __builtin_amdgcn_s_sleep(1);
            if (++guard > 1000000) break;
        }
    }
    __syncthreads();

    for (int k = 0; k <= Sn; ++k) {
        // ---- stage h_{k-1} (ring slot (k&1)^1): two f32x4/thread, L2-local ----
        const int slot = (k & 1) ^ 1;
        {
            const float* p0 = ring + (size_t)slot * 4096 + 4 * t;
            const float* p1 = p0 + 2048;
            f32x4 v0, v1;
            asm volatile(
                "global_load_dwordx4 %0, %2, off sc0\n\t"
                "global_load_dwordx4 %1, %3, off sc0\n\t"
                "s_waitcnt vmcnt(0)"
                : "=&v"(v0), "=&v"(v1)
                : "v"(p0), "v"(p1) : "memory");
            int fi = t;
            *(f32x4*)&hx[fi >> 7][(fi & 127) * 4] = v0;
            fi = t + 512;
            *(f32x4*)&hx[fi >> 7][(fi & 127) * 4] = v1;
        }
        if (k < Sn && t < 256) {  // stage x[:,k,:] for our 8 batches (cached loads)
            const int bbs = t >> 5, f4 = (t & 31) * 4;
            const f32x4 v = *(const f32x4*)(x + (size_t)(8 * bw + bbs) * Sn * Fn +
                                            (size_t)k * Fn + f4);
            *(f32x4*)&hx[bbs][Hn + f4] = v;
        }
        __syncthreads();

        // ---- gate GEMM: acc[2 rows][8 batches] over K-slice [k0,k0+20) ----
        if (k < Sn) {
            float acc[2][8];
#pragma unroll
            for (int i = 0; i < 2; ++i)
#pragma unroll
                for (int ib = 0; ib < 8; ++ib) acc[i][ib] = 0.0f;
#pragma unroll
            for (int j = 0; j < 5; ++j) {
                f32x4 hv[4];
#pragma unroll
                for (int ib = 0; ib < 4; ++ib)
                    hv[ib] = *(const f32x4*)&hx[ib][k0 + 4 * j];
#pragma unroll
                for (int i = 0; i < 2; ++i)
#pragma unroll
                    for (int ib = 0; ib < 4; ++ib)
                        acc[i][ib] += wreg[i][j].x * hv[ib].x + wreg[i][j].y * hv[ib].y +
                                      wreg[i][j].z * hv[ib].z + wreg[i][j].w * hv[ib].w;
#pragma unroll
                for (int ib = 0; ib < 4; ++ib)
                    hv[ib] = *(const f32x4*)&hx[4 + ib][k0 + 4 * j];
#pragma unroll
                for (int i = 0; i < 2; ++i)
#pragma unroll
                    for (int ib = 0; ib < 4; ++ib)
                        acc[i][4 + ib] += wreg[i][j].x * hv[ib].x + wreg[i][j].y * hv[ib].y +
                                          wreg[i][j].z * hv[ib].z + wreg[i][j].w * hv[ib].w;
            }
#pragma unroll
            for (int i = 0; i < 2; ++i)
#pragma unroll
                for (int ib = 0; ib < 8; ++ib)
                    part[q * PQS + (2 * r2 + i) * 9 + ib] = acc[i][ib];
        }

        // ---- pipelined out-projection for step k-1 (uses staged h_{k-1}) ----
        if (k >= 1 && t < 256) {
            const float* wo = Wout + (size_t)(rw * 2 + out_fi) * Hn + out_ksl * 32;
            const float* hrow = &hx[out_bb][out_ksl * 32];
            float oa = 0.0f;
#pragma unroll
            for (int jj = 0; jj < 8; ++jj) {
                const f32x4 wv = *(const f32x4*)(wo + 4 * jj);
                const f32x4 hv = *(const f32x4*)(hrow + 4 * jj);
                oa += wv.x * hv.x + wv.y * hv.y + wv.z * hv.z + wv.w * hv.w;
            }
            opart[out_fi][out_bb][out_ksl] = oa;
        }
        __syncthreads();

        // ---- cell update (t<128, gate-pair split + shfl) ----
        if (k < Sn && t < 128) {
            const int gh = t & 1, ul = (t >> 1) & 7, bbc = (t >> 4) & 7;
            const int r0 = 16 * gh + ul, r1 = 16 * gh + 8 + ul;
            float s0 = gb[r0], s1 = gb[r1];
#pragma unroll
            for (int qq = 0; qq < 32; ++qq) {
                s0 += part[qq * PQS + r0 * 9 + bbc];
                s1 += part[qq * PQS + r1 * 9 + bbc];
            }
            const float o0 = __shfl_xor(s0, 1, 64);
            const float o1 = __shfl_xor(s1, 1, 64);
            if (gh == 0) {
                const float ig = sigmoid_f(s0);
                const float fg = sigmoid_f(s1);
                const float gg = tanh_f(o0);
                const float og = sigmoid_f(o1);
                const float cn = fg * cst[ul][bbc] + ig * gg;
                cst[ul][bbc] = cn;
                const float hn = og * tanh_f(cn);
                float* hdst = ring + (size_t)(k & 1) * 4096 +
                              (size_t)bbc * 512 + (8 * rw + ul);
                asm volatile("global_store_dword %0, %1, off sc0"
                             :: "v"(hdst), "v"(hn) : "memory");
            }
        } else if (k >= 1 && t >= 256 && t < 272) {
            // ---- out finalize for step k-1: 2 feats x 8 batches ----
            const int fi = (t - 256) >> 3, bbo = (t - 256) & 7;
            float s = bo[fi];
#pragma unroll
            for (int qq = 0; qq < 16; ++qq) s += opart[fi][bbo][qq];
            out[(size_t)(8 * bw + bbo) * Sn * Fn + (size_t)(k - 1) * Fn +
                rw * 2 + fi] = s;
        }

        // ---- single-level 64-WG (same-XCD) barrier, t==0 polls ----
        if (k < Sn) {
            asm volatile("s_waitcnt vmcnt(0)" ::: "memory");  // h stores are in L2
            __syncthreads();
            if (t == 0) {
                atomicAdd(gcnt, 1u);
                const unsigned target = 64u * (unsigned)(k + 2);
                int guard = 0;
                while (__hip_atomic_load(gcnt, __ATOMIC_RELAXED,
                                         __HIP_MEMORY_SCOPE_AGENT) < target) {
                    __builtin_amdgcn_s_sleep(1);
                    if (++guard > 100000) break;  // fail loud, never hang
                }
            }
            __syncthreads();
        }
    }
}

extern "C" void kernel_launch(void* const* d_in, const int* in_sizes, int n_in,
                              void* d_out, int out_size, void* d_ws, size_t ws_size,
                              hipStream_t stream) {
    (void)in_sizes; (void)n_in; (void)out_size; (void)ws_size;
    const float* x    = (const float*)d_in[0];
    const float* Wih  = (const float*)d_in[1];
    const float* Whh  = (const float*)d_in[2];
    const float* bih  = (const float*)d_in[3];
    const float* bhh  = (const float*)d_in[4];
    const float* Wout = (const float*)d_in[5];
    const float* bout = (const float*)d_in[6];
    float* outp = (float*)d_out;
    float* wsp  = (float*)d_ws;  // [4 KB counters+tickets][8 x 32 KB group h rings]

    hipMemsetAsync(d_ws, 0, 4096, stream);  // barrier counters + slot tickets

    lstm_persist<<<dim3(NWG), dim3(NTHR), 0, stream>>>(
        x, Wih, Whh, bih, bhh, Wout, bout, outp, wsp);
}